// Round 9
// baseline (189.990 us; speedup 1.0000x reference)
//
#include <hip/hip_runtime.h>
#include <hip/hip_bf16.h>
#include <stdint.h>

#define NTLS 16384

typedef float f32x4 __attribute__((ext_vector_type(4)));
typedef short bf16x8 __attribute__((ext_vector_type(8)));
typedef short bf16x4 __attribute__((ext_vector_type(4)));

// packed fp32->bf16 (RNE) via native instruction
__device__ __forceinline__ unsigned pk2(float a, float b){
    unsigned r;
    asm("v_cvt_pk_bf16_f32 %0, %1, %2" : "=v"(r) : "v"(a), "v"(b));
    return r;
}
__device__ __forceinline__ short f2bf(float x){
    return (short)(pk2(x, 0.f) & 0xffff);
}
__device__ __forceinline__ unsigned lds_lo(const void* p){
    return (unsigned)(size_t)p;
}
__device__ __forceinline__ bf16x4 ds_tr(unsigned addr){
    bf16x4 d;
    asm volatile("ds_read_b64_tr_b16 %0, %1" : "=v"(d) : "v"(addr) : "memory");
    return d;
}
__device__ __forceinline__ void lgkm0(){
    asm volatile("s_waitcnt lgkmcnt(0)" ::: "memory");
    __builtin_amdgcn_sched_barrier(0);
}
// ATOMIC load-4-fragments + waitcnt in ONE asm block. The waitcnt is inside the
// block, so no copy/spill/consumer can be interposed while loads are in flight
// (rule-#18 hazard). "=&v" early-clobber: outputs never alias the address pair.
// Frag stride 1024B; offsets 0..3072 fit the 13-bit signed global offset.
__device__ __forceinline__ void gload4_wait(const short* base,
        bf16x8& d0, bf16x8& d1, bf16x8& d2, bf16x8& d3){
    asm volatile(
        "global_load_dwordx4 %0, %4, off\n\t"
        "global_load_dwordx4 %1, %4, off offset:1024\n\t"
        "global_load_dwordx4 %2, %4, off offset:2048\n\t"
        "global_load_dwordx4 %3, %4, off offset:3072\n\t"
        "s_waitcnt vmcnt(0)"
        : "=&v"(d0), "=&v"(d1), "=&v"(d2), "=&v"(d3)
        : "v"(base)
        : "memory");
}
__device__ __forceinline__ bf16x8 cat44(bf16x4 lo, bf16x4 hi){
    bf16x8 r;
    r[0]=lo[0]; r[1]=lo[1]; r[2]=lo[2]; r[3]=lo[3];
    r[4]=hi[0]; r[5]=hi[1]; r[6]=hi[2]; r[7]=hi[3];
    return r;
}
__device__ __forceinline__ bf16x8 cat40(bf16x4 lo){
    bf16x8 r;
    r[0]=lo[0]; r[1]=lo[1]; r[2]=lo[2]; r[3]=lo[3];
    r[4]=0; r[5]=0; r[6]=0; r[7]=0;
    return r;
}
#define MFMA16(a,b,c) __builtin_amdgcn_mfma_f32_16x16x32_bf16((a),(b),(c),0,0,0)

// ---------------- weight prepack (verified): fp32 row-major -> bf16 frag-linear
__global__ __launch_bounds__(256) void prepack(
    const float* __restrict__ W2, const float* __restrict__ Wq,
    const float* __restrict__ Wk, const float* __restrict__ Wv,
    const float* __restrict__ Wo, const float* __restrict__ Wp2,
    const float* __restrict__ Wf1, const float* __restrict__ Wf2,
    short* __restrict__ out)
{
    int gid = blockIdx.x * 256 + threadIdx.x;      // 0..29695
    const float* src; short* dst; int K, Nn; int id = gid;
    if (id < 12288){
        int wsel = id >> 11; id &= 2047;
        const float* tab[6] = {W2, Wq, Wk, Wv, Wo, Wp2};
        src = tab[wsel]; dst = out + wsel * 16384; K = 128; Nn = 128;
    } else if (id < 21504){
        id -= 12288; src = Wf1; dst = out + 98304; K = 288; Nn = 256;
    } else {
        id -= 21504; src = Wf2; dst = out + 172032; K = 256; Nn = 256;
    }
    int lane = id & 63, f = id >> 6;
    int KT = K >> 5;
    int nt = f / KT, kt = f - nt * KT;
    int n  = nt * 16 + (lane & 15);
    int kb = kt * 32 + 4 * (lane >> 4);
    unsigned w0 = pk2(src[(kb+0)*Nn+n],  src[(kb+1)*Nn+n]);
    unsigned w1 = pk2(src[(kb+2)*Nn+n],  src[(kb+3)*Nn+n]);
    unsigned w2 = pk2(src[(kb+16)*Nn+n], src[(kb+17)*Nn+n]);
    unsigned w3 = pk2(src[(kb+18)*Nn+n], src[(kb+19)*Nn+n]);
    *(uint4*)&dst[(f*64+lane)*8] = make_uint4(w0,w1,w2,w3);
}

// ============ kernel 1: lane pipeline, 8 TLS/block, 8 waves, head-per-wave ============
__global__ __launch_bounds__(512, 4) void k1_lane(
    const float* __restrict__ queues, const float* __restrict__ waits,
    const float* __restrict__ elapsed, const int* __restrict__ lane_counts,
    const float* __restrict__ W1, const float* __restrict__ b1,
    const float* __restrict__ b2,
    const float* __restrict__ bq, const float* __restrict__ bk_, const float* __restrict__ bv_,
    const short* __restrict__ wpk,
    short* __restrict__ meanb)
{
    const int tid  = threadIdx.x;
    const int w    = tid >> 6, lane = tid & 63;
    const int nl   = lane & 15, kb = lane >> 4;
    const int base = blockIdx.x << 3;

    __shared__ __align__(512) short s_h1[8*2048];   // 32KB; stage C: wave-private qkv bufs
    __shared__ __align__(512) short s_emb[8*2048];  // 32KB

    const unsigned trofs = (unsigned)(kb*128 + nl*8);
    const short* Wpk2 = wpk;
    const short* WpkQ = wpk + 16384;
    const short* WpkK = wpk + 32768;
    const short* WpkV = wpk + 49152;

    // ---- stage A: wave w computes h1 for TLS w (all 128 cols, 16 rows)
    {
        const int n = base + w;
        const float ev = elapsed[n];
        float qv = queues[n*16 + nl];
        float wv = waits [n*16 + nl];
        float qm[4], wmv[4];
        #pragma unroll
        for (int r = 0; r < 4; ++r){
            qm[r]  = __shfl(qv, 4*kb + r, 16);
            wmv[r] = __shfl(wv, 4*kb + r, 16);
        }
        #pragma unroll
        for (int i = 0; i < 8; ++i){
            int c = nl + 16*i;
            float w0 = W1[c], w1 = W1[128+c], w2 = W1[256+c], bb = b1[c];
            float v0 = fmaxf(fmaf(qm[0], w0, fmaf(wmv[0], w1, fmaf(ev, w2, bb))), 0.f);
            float v1 = fmaxf(fmaf(qm[1], w0, fmaf(wmv[1], w1, fmaf(ev, w2, bb))), 0.f);
            float v2 = fmaxf(fmaf(qm[2], w0, fmaf(wmv[2], w1, fmaf(ev, w2, bb))), 0.f);
            float v3 = fmaxf(fmaf(qm[3], w0, fmaf(wmv[3], w1, fmaf(ev, w2, bb))), 0.f);
            *(uint2*)&s_h1[w*2048 + c*16 + 4*kb] = make_uint2(pk2(v0,v1), pk2(v2,v3));
        }
    }
    __syncthreads();

    // ---- stage B: emb = relu(h1 @ W2 + b2); wave w owns cols [16w,16w+16), loops 8 TLS
    {
        bf16x8 B2[4];
        gload4_wait(Wpk2 + ((w*4)*64 + lane)*8, B2[0], B2[1], B2[2], B2[3]);
        const int c0 = 16*w + nl;
        const float bb0 = b2[c0];
        for (int t = 0; t < 8; ++t){
            unsigned ab = lds_lo(s_h1) + t*4096 + trofs;
            bf16x4 tr[8];
            #pragma unroll
            for (int kt = 0; kt < 4; ++kt){
                tr[2*kt]   = ds_tr(ab + kt*1024);
                tr[2*kt+1] = ds_tr(ab + kt*1024 + 512);
            }
            lgkm0();
            f32x4 a0 = {0.f,0.f,0.f,0.f};
            #pragma unroll
            for (int kt = 0; kt < 4; ++kt)
                a0 = MFMA16(cat44(tr[2*kt], tr[2*kt+1]), B2[kt], a0);
            *(uint2*)&s_emb[t*2048 + c0*16 + 4*kb] =
                make_uint2(pk2(fmaxf(a0[0]+bb0,0.f), fmaxf(a0[1]+bb0,0.f)),
                           pk2(fmaxf(a0[2]+bb0,0.f), fmaxf(a0[3]+bb0,0.f)));
        }
    }
    __syncthreads();   // all stage-B reads of s_h1 done -> safe to overlay qkv bufs

    // ---- stage C + attention: wave w owns head w (cols [16w,16w+16))
    {
        bf16x8 BQ[4], BK[4], BV[4];
        gload4_wait(WpkQ + ((w*4)*64 + lane)*8, BQ[0], BQ[1], BQ[2], BQ[3]);
        gload4_wait(WpkK + ((w*4)*64 + lane)*8, BK[0], BK[1], BK[2], BK[3]);
        gload4_wait(WpkV + ((w*4)*64 + lane)*8, BV[0], BV[1], BV[2], BV[3]);
        const int c0 = 16*w + nl;
        const float xq = bq[c0], xk = bk_[c0], xv = bv_[c0];
        short* wbuf = s_h1 + w*2048;          // wave-private 4KB (2 bufs x 2KB)
        const f32x4 zero = {0.f,0.f,0.f,0.f};

        for (int t = 0; t < 8; ++t){
            const int n = base + t;
            const int L = lane_counts[n];
            const float invL = 1.f / (float)L;

            unsigned ab = lds_lo(s_emb) + t*4096 + trofs;
            bf16x4 tr[8];
            #pragma unroll
            for (int kt = 0; kt < 4; ++kt){
                tr[2*kt]   = ds_tr(ab + kt*1024);
                tr[2*kt+1] = ds_tr(ab + kt*1024 + 512);
            }
            lgkm0();
            f32x4 q0=zero, k0=zero, v0=zero;
            #pragma unroll
            for (int kt = 0; kt < 4; ++kt){
                bf16x8 A = cat44(tr[2*kt], tr[2*kt+1]);
                q0 = MFMA16(A, BQ[kt], q0);
                k0 = MFMA16(A, BK[kt], k0);
                v0 = MFMA16(A, BV[kt], v0);
            }
            // q shorts [0,256) | k [256,512) | v [512,768)
            short* buf = wbuf + (t&1)*1024;
            *(uint2*)&buf[nl*16 + 4*kb] =
                make_uint2(pk2(q0[0]+xq, q0[1]+xq), pk2(q0[2]+xq, q0[3]+xq));
            *(uint2*)&buf[256 + nl*16 + 4*kb] =
                make_uint2(pk2(k0[0]+xk, k0[1]+xk), pk2(k0[2]+xk, k0[3]+xk));
            *(uint2*)&buf[512 + nl*16 + 4*kb] =
                make_uint2(pk2(v0[0]+xv, v0[1]+xv), pk2(v0[2]+xv, v0[3]+xv));
            lgkm0();

            const unsigned ba = lds_lo(buf);
            bf16x4 qf = ds_tr(ba + trofs);
            bf16x4 kf = ds_tr(ba + 512 + trofs);
            bf16x4 vf = *(const bf16x4*)&buf[512 + nl*16 + 4*kb];
            lgkm0();

            f32x4 st = MFMA16(cat40(kf), cat40(qf), zero);  // rows j=4kb+r, col i=nl
            // softmax over key rows j (no max-sub: |score| << 1 for this model scale)
            float pr[4], ps = 0.f;
            #pragma unroll
            for (int r = 0; r < 4; ++r){
                pr[r] = (4*kb+r < L) ? __expf(st[r]*0.25f) : 0.f;
                ps += pr[r];
            }
            ps += __shfl_xor(ps, 16);
            ps += __shfl_xor(ps, 32);
            float inv = 1.f/ps;
            union { bf16x8 v; unsigned u[4]; } P;
            P.u[0] = pk2(pr[0]*inv, pr[1]*inv);
            P.u[1] = pk2(pr[2]*inv, pr[3]*inv);
            P.u[2] = 0; P.u[3] = 0;
            f32x4 ctx = MFMA16(P.v, cat40(vf), zero);       // rows i=4kb+r, col d=nl
            float pm = 0.f;
            #pragma unroll
            for (int r = 0; r < 4; ++r) if (4*kb+r < L) pm += ctx[r];
            pm += __shfl_xor(pm, 16);
            pm += __shfl_xor(pm, 32);
            if (kb == 0)
                meanb[((n>>4)<<11) + c0*16 + (n&15)] = f2bf(pm * invL);
        }
    }
}

// ============ kernel 2: tail (round-4 verified version), 32 TLS/block, 4 waves ============
__global__ __launch_bounds__(256, 2) void k2_tail(
    const float* __restrict__ phase_onehot, const float* __restrict__ elapsed,
    const int* __restrict__ region_ids, const float* __restrict__ region_table,
    const float* __restrict__ Wp1, const float* __restrict__ bp1, const float* __restrict__ bp2,
    const float* __restrict__ bo,
    const float* __restrict__ bf1, const float* __restrict__ bf2_,
    const float* __restrict__ Wm, const float* __restrict__ bm,
    const float* __restrict__ Wval, const float* __restrict__ bval,
    const float* __restrict__ log_std,
    const short* __restrict__ wpk, const short* __restrict__ meanb,
    float* __restrict__ out)
{
    const int tid  = threadIdx.x;
    const int w    = tid >> 6, lane = tid & 63;
    const int nl   = lane & 15, kb = lane >> 4;
    const int base = blockIdx.x << 5;   // 32 TLS

    __shared__ __align__(512) short s_mean[2*2048];   // 8 KB
    __shared__ __align__(512) short s_ph1[2*2048];    // 8 KB
    __shared__ __align__(512) short s_fused[2*4608];  // 18 KB
    __shared__ __align__(512) short s_hf[2*4096];     // 16 KB
    __shared__ float s_part[4][2][16][2];             // 1 KB

    const unsigned trofs = (unsigned)(kb*128 + nl*8);
    const bf16x8* WpkO  = (const bf16x8*)(wpk + 65536);
    const bf16x8* WpkP2 = (const bf16x8*)(wpk + 81920);
    const bf16x8* WpkF1 = (const bf16x8*)(wpk + 98304);
    const bf16x8* WpkF2 = (const bf16x8*)(wpk + 172032);

    // 1. copy mean chunk (already col-major-16 in global) -> LDS, linear
    {
        const uint4* src = (const uint4*)(meanb + base*128);
        uint4* dst = (uint4*)s_mean;
        dst[tid]       = src[tid];
        dst[256 + tid] = src[256 + tid];
    }
    // 2. phase hidden: thread -> TLS r = tid>>3, cols 16*(tid&7)..+16
    {
        const int r = tid >> 3, cb = tid & 7, n = base + r;
        const float p0 = phase_onehot[n*4+0], p1 = phase_onehot[n*4+1];
        const float p2 = phase_onehot[n*4+2], p3 = phase_onehot[n*4+3];
        const float ev = elapsed[n];
        #pragma unroll
        for (int jc = 0; jc < 16; ++jc){
            int c = cb*16 + jc;
            float a = fmaf(p0, Wp1[c], fmaf(p1, Wp1[128+c], fmaf(p2, Wp1[256+c],
                      fmaf(p3, Wp1[384+c], fmaf(ev, Wp1[512+c], bp1[c])))));
            s_ph1[(r>>4)*2048 + c*16 + (r&15)] = f2bf(fmaxf(a, 0.f));
        }
        // 3. region embedding -> fused cols [256,288)
        const int rid = region_ids[n];
        #pragma unroll
        for (int jc = 0; jc < 4; ++jc){
            int c = (tid&7)*4 + jc;
            s_fused[(r>>4)*4608 + (256+c)*16 + (r&15)] = f2bf(region_table[rid*32 + c]);
        }
    }
    __syncthreads();

    // 4. Wo (no relu) + Wp2 (relu): wave w owns nt {2w,2w+1}
    {
        bf16x8 BO[8], BP[8];
        #pragma unroll
        for (int nt2 = 0; nt2 < 2; ++nt2)
            #pragma unroll
            for (int kt = 0; kt < 4; ++kt){
                int fi = ((2*w+nt2)*4+kt)*64 + lane;
                BO[nt2*4+kt] = WpkO[fi];
                BP[nt2*4+kt] = WpkP2[fi];
            }
        const int c0 = 32*w + nl, c1 = c0 + 16;
        const float o0b = bo[c0], o1b = bo[c1];
        const float p0b = bp2[c0], p1b = bp2[c1];
        #pragma unroll
        for (int mt = 0; mt < 2; ++mt){
            unsigned am = lds_lo(s_mean) + mt*4096 + trofs;
            unsigned ap = lds_lo(s_ph1)  + mt*4096 + trofs;
            bf16x4 t[16];
            #pragma unroll
            for (int kt = 0; kt < 4; ++kt){
                t[2*kt]     = ds_tr(am + kt*1024);
                t[2*kt+1]   = ds_tr(am + kt*1024 + 512);
                t[8+2*kt]   = ds_tr(ap + kt*1024);
                t[9+2*kt]   = ds_tr(ap + kt*1024 + 512);
            }
            lgkm0();
            f32x4 o0={0.f,0.f,0.f,0.f}, o1=o0, p0=o0, p1=o0;
            #pragma unroll
            for (int kt = 0; kt < 4; ++kt){
                bf16x8 Am = cat44(t[2*kt],   t[2*kt+1]);
                bf16x8 Ap = cat44(t[8+2*kt], t[9+2*kt]);
                o0 = MFMA16(Am, BO[kt],   o0);
                o1 = MFMA16(Am, BO[4+kt], o1);
                p0 = MFMA16(Ap, BP[kt],   p0);
                p1 = MFMA16(Ap, BP[4+kt], p1);
            }
            short* fb = s_fused + mt*4608;
            *(uint2*)&fb[c0*16 + 4*kb] =
                make_uint2(pk2(o0[0]+o0b, o0[1]+o0b), pk2(o0[2]+o0b, o0[3]+o0b));
            *(uint2*)&fb[c1*16 + 4*kb] =
                make_uint2(pk2(o1[0]+o1b, o1[1]+o1b), pk2(o1[2]+o1b, o1[3]+o1b));
            *(uint2*)&fb[(128+c0)*16 + 4*kb] =
                make_uint2(pk2(fmaxf(p0[0]+p0b,0.f), fmaxf(p0[1]+p0b,0.f)),
                           pk2(fmaxf(p0[2]+p0b,0.f), fmaxf(p0[3]+p0b,0.f)));
            *(uint2*)&fb[(128+c1)*16 + 4*kb] =
                make_uint2(pk2(fmaxf(p1[0]+p1b,0.f), fmaxf(p1[1]+p1b,0.f)),
                           pk2(fmaxf(p1[2]+p1b,0.f), fmaxf(p1[3]+p1b,0.f)));
        }
    }
    __syncthreads();

    // 5. F1: hf = relu(fused @ Wf1 + bf1), K=288; wave w owns nt {4w..4w+3}
    {
        bf16x8 A[2][9];
        #pragma unroll
        for (int mt = 0; mt < 2; ++mt){
            unsigned ab = lds_lo(s_fused) + mt*9216 + trofs;
            bf16x4 t[18];
            #pragma unroll
            for (int kt = 0; kt < 9; ++kt){
                t[2*kt]   = ds_tr(ab + kt*1024);
                t[2*kt+1] = ds_tr(ab + kt*1024 + 512);
            }
            lgkm0();
            #pragma unroll
            for (int kt = 0; kt < 9; ++kt) A[mt][kt] = cat44(t[2*kt], t[2*kt+1]);
        }
        #pragma unroll
        for (int nt2 = 0; nt2 < 4; ++nt2){
            const int nt = 4*w + nt2;
            bf16x8 Bf[9];
            #pragma unroll
            for (int kt = 0; kt < 9; ++kt) Bf[kt] = WpkF1[(nt*9+kt)*64 + lane];
            f32x4 a0 = {0.f,0.f,0.f,0.f}, a1 = a0;
            #pragma unroll
            for (int kt = 0; kt < 9; ++kt){
                a0 = MFMA16(A[0][kt], Bf[kt], a0);
                a1 = MFMA16(A[1][kt], Bf[kt], a1);
            }
            const int c = nt*16 + nl;
            const float bb = bf1[c];
            *(uint2*)&s_hf[c*16 + 4*kb] =
                make_uint2(pk2(fmaxf(a0[0]+bb,0.f), fmaxf(a0[1]+bb,0.f)),
                           pk2(fmaxf(a0[2]+bb,0.f), fmaxf(a0[3]+bb,0.f)));
            *(uint2*)&s_hf[4096 + c*16 + 4*kb] =
                make_uint2(pk2(fmaxf(a1[0]+bb,0.f), fmaxf(a1[1]+bb,0.f)),
                           pk2(fmaxf(a1[2]+bb,0.f), fmaxf(a1[3]+bb,0.f)));
        }
    }
    __syncthreads();

    // 6. F2 + heads epilogue: wave w owns nt {4w..4w+3}
    {
        bf16x8 A[2][8];
        #pragma unroll
        for (int mt = 0; mt < 2; ++mt){
            unsigned ab = lds_lo(s_hf) + mt*8192 + trofs;
            bf16x4 t[16];
            #pragma unroll
            for (int kt = 0; kt < 8; ++kt){
                t[2*kt]   = ds_tr(ab + kt*1024);
                t[2*kt+1] = ds_tr(ab + kt*1024 + 512);
            }
            lgkm0();
            #pragma unroll
            for (int kt = 0; kt < 8; ++kt) A[mt][kt] = cat44(t[2*kt], t[2*kt+1]);
        }
        float sm0[4] = {0,0,0,0}, sv0[4] = {0,0,0,0};
        float sm1[4] = {0,0,0,0}, sv1[4] = {0,0,0,0};
        #pragma unroll
        for (int nt2 = 0; nt2 < 4; ++nt2){
            const int nt = 4*w + nt2;
            bf16x8 Bf[8];
            #pragma unroll
            for (int kt = 0; kt < 8; ++kt) Bf[kt] = WpkF2[(nt*8+kt)*64 + lane];
            f32x4 a0 = {0.f,0.f,0.f,0.f}, a1 = a0;
            #pragma unroll
            for (int kt = 0; kt < 8; ++kt){
                a0 = MFMA16(A[0][kt], Bf[kt], a0);
                a1 = MFMA16(A[1][kt], Bf[kt], a1);
            }
            const int c = nt*16 + nl;
            const float bb = bf2_[c], wm = Wm[c], wv = Wval[c];
            #pragma unroll
            for (int r = 0; r < 4; ++r){
                float h0 = fmaxf(a0[r]+bb, 0.f);
                float h1 = fmaxf(a1[r]+bb, 0.f);
                sm0[r] = fmaf(h0, wm, sm0[r]);  sv0[r] = fmaf(h0, wv, sv0[r]);
                sm1[r] = fmaf(h1, wm, sm1[r]);  sv1[r] = fmaf(h1, wv, sv1[r]);
            }
        }
        #pragma unroll
        for (int off = 1; off < 16; off <<= 1){
            #pragma unroll
            for (int r = 0; r < 4; ++r){
                sm0[r] += __shfl_xor(sm0[r], off);  sv0[r] += __shfl_xor(sv0[r], off);
                sm1[r] += __shfl_xor(sm1[r], off);  sv1[r] += __shfl_xor(sv1[r], off);
            }
        }
        if (nl == 0){
            #pragma unroll
            for (int r = 0; r < 4; ++r){
                s_part[w][0][4*kb+r][0] = sm0[r];  s_part[w][0][4*kb+r][1] = sv0[r];
                s_part[w][1][4*kb+r][0] = sm1[r];  s_part[w][1][4*kb+r][1] = sv1[r];
            }
        }
    }
    __syncthreads();

    // 7. finalize
    if (tid < 32){
        const int r = tid, n = base + r;
        float sm = bm[0], sv = bval[0];
        #pragma unroll
        for (int ww = 0; ww < 4; ++ww){
            sm += s_part[ww][r>>4][r&15][0];
            sv += s_part[ww][r>>4][r&15][1];
        }
        out[n]          = sm;
        out[NTLS + n]   = log_std[0];
        out[2*NTLS + n] = sv;
    }
}

extern "C" void kernel_launch(void* const* d_in, const int* in_sizes, int n_in,
                              void* d_out, int out_size, void* d_ws, size_t ws_size,
                              hipStream_t stream) {
    const float* queues       = (const float*)d_in[0];
    const float* waits        = (const float*)d_in[1];
    const float* phase_onehot = (const float*)d_in[2];
    const float* elapsed      = (const float*)d_in[3];
    const int*   lane_counts  = (const int*)d_in[4];
    const int*   region_ids   = (const int*)d_in[5];
    const float* W1  = (const float*)d_in[6];
    const float* b1  = (const float*)d_in[7];
    const float* W2  = (const float*)d_in[8];
    const float* b2  = (const float*)d_in[9];
    const float* Wq  = (const float*)d_in[10];
    const float* bq  = (const float*)d_in[11];
    const float* Wk  = (const float*)d_in[12];
    const float* bk  = (const float*)d_in[13];
    const float* Wv  = (const float*)d_in[14];
    const float* bv  = (const float*)d_in[15];
    const float* Wo  = (const float*)d_in[16];
    const float* bo  = (const float*)d_in[17];
    const float* Wp1 = (const float*)d_in[18];
    const float* bp1 = (const float*)d_in[19];
    const float* Wp2 = (const float*)d_in[20];
    const float* bp2 = (const float*)d_in[21];
    const float* region_table = (const float*)d_in[22];
    const float* Wf1 = (const float*)d_in[23];
    const float* bf1 = (const float*)d_in[24];
    const float* Wf2 = (const float*)d_in[25];
    const float* bf2 = (const float*)d_in[26];
    const float* Wm  = (const float*)d_in[27];
    const float* bm  = (const float*)d_in[28];
    const float* Wval = (const float*)d_in[29];
    const float* bval = (const float*)d_in[30];
    const float* log_std = (const float*)d_in[31];
    float* out = (float*)d_out;

    short* wpk   = (short*)d_ws;                          // 475136 B packed weights
    short* meanb = (short*)((char*)d_ws + 524288);        // 4 MB col-major-16 mean

    prepack<<<116, 256, 0, stream>>>(W2, Wq, Wk, Wv, Wo, Wp2, Wf1, Wf2, wpk);
    k1_lane<<<2048, 512, 0, stream>>>(
        queues, waits, elapsed, lane_counts,
        W1, b1, b2, bq, bk, bv, wpk, meanb);
    k2_tail<<<512, 256, 0, stream>>>(
        phase_onehot, elapsed, region_ids, region_table,
        Wp1, bp1, bp2, bo, bf1, bf2, Wm, bm, Wval, bval, log_std,
        wpk, meanb, out);
}

// Round 11
// 188.371 us; speedup vs baseline: 1.0086x; 1.0086x over previous
//
#include <hip/hip_runtime.h>
#include <hip/hip_bf16.h>
#include <stdint.h>

#define NTLS 16384

typedef float f32x4 __attribute__((ext_vector_type(4)));
typedef short bf16x8 __attribute__((ext_vector_type(8)));
typedef short bf16x4 __attribute__((ext_vector_type(4)));

// packed fp32->bf16 (RNE) via native instruction
__device__ __forceinline__ unsigned pk2(float a, float b){
    unsigned r;
    asm("v_cvt_pk_bf16_f32 %0, %1, %2" : "=v"(r) : "v"(a), "v"(b));
    return r;
}
__device__ __forceinline__ short f2bf(float x){
    return (short)(pk2(x, 0.f) & 0xffff);
}
__device__ __forceinline__ unsigned lds_lo(const void* p){
    return (unsigned)(size_t)p;
}
__device__ __forceinline__ bf16x4 ds_tr(unsigned addr){
    bf16x4 d;
    asm volatile("ds_read_b64_tr_b16 %0, %1" : "=v"(d) : "v"(addr) : "memory");
    return d;
}
__device__ __forceinline__ void lgkm0(){
    asm volatile("s_waitcnt lgkmcnt(0)" ::: "memory");
    __builtin_amdgcn_sched_barrier(0);
}
// ATOMIC: 4 fragment loads + vmcnt(0) in ONE asm block (r9-proven correct).
__device__ __forceinline__ void gload4_wait(const short* base,
        bf16x8& d0, bf16x8& d1, bf16x8& d2, bf16x8& d3){
    asm volatile(
        "global_load_dwordx4 %0, %4, off\n\t"
        "global_load_dwordx4 %1, %4, off offset:1024\n\t"
        "global_load_dwordx4 %2, %4, off offset:2048\n\t"
        "global_load_dwordx4 %3, %4, off offset:3072\n\t"
        "s_waitcnt vmcnt(0)"
        : "=&v"(d0), "=&v"(d1), "=&v"(d2), "=&v"(d3)
        : "v"(base)
        : "memory");
}
__device__ __forceinline__ bf16x8 cat44(bf16x4 lo, bf16x4 hi){
    bf16x8 r;
    r[0]=lo[0]; r[1]=lo[1]; r[2]=lo[2]; r[3]=lo[3];
    r[4]=hi[0]; r[5]=hi[1]; r[6]=hi[2]; r[7]=hi[3];
    return r;
}
__device__ __forceinline__ bf16x8 cat40(bf16x4 lo){
    bf16x8 r;
    r[0]=lo[0]; r[1]=lo[1]; r[2]=lo[2]; r[3]=lo[3];
    r[4]=0; r[5]=0; r[6]=0; r[7]=0;
    return r;
}
#define MFMA16(a,b,c) __builtin_amdgcn_mfma_f32_16x16x32_bf16((a),(b),(c),0,0,0)

// ---------------- weight prepack (verified): fp32 row-major -> bf16 frag-linear
__global__ __launch_bounds__(256) void prepack(
    const float* __restrict__ W2, const float* __restrict__ Wq,
    const float* __restrict__ Wk, const float* __restrict__ Wv,
    const float* __restrict__ Wo, const float* __restrict__ Wp2,
    const float* __restrict__ Wf1, const float* __restrict__ Wf2,
    short* __restrict__ out)
{
    int gid = blockIdx.x * 256 + threadIdx.x;      // 0..29695
    const float* src; short* dst; int K, Nn; int id = gid;
    if (id < 12288){
        int wsel = id >> 11; id &= 2047;
        const float* tab[6] = {W2, Wq, Wk, Wv, Wo, Wp2};
        src = tab[wsel]; dst = out + wsel * 16384; K = 128; Nn = 128;
    } else if (id < 21504){
        id -= 12288; src = Wf1; dst = out + 98304; K = 288; Nn = 256;
    } else {
        id -= 21504; src = Wf2; dst = out + 172032; K = 256; Nn = 256;
    }
    int lane = id & 63, f = id >> 6;
    int KT = K >> 5;
    int nt = f / KT, kt = f - nt * KT;
    int n  = nt * 16 + (lane & 15);
    int kb = kt * 32 + 4 * (lane >> 4);
    unsigned w0 = pk2(src[(kb+0)*Nn+n],  src[(kb+1)*Nn+n]);
    unsigned w1 = pk2(src[(kb+2)*Nn+n],  src[(kb+3)*Nn+n]);
    unsigned w2 = pk2(src[(kb+16)*Nn+n], src[(kb+17)*Nn+n]);
    unsigned w3 = pk2(src[(kb+18)*Nn+n], src[(kb+19)*Nn+n]);
    *(uint4*)&dst[(f*64+lane)*8] = make_uint4(w0,w1,w2,w3);
}

// ============ kernel 1: lane pipeline, 8 TLS/block, 8 waves, head-per-wave ============
// r9-proven structure; stages B and C process TWO TLS per iteration (independent
// chains interleave in the scheduler -> halved exposed latency, shared waits).
__global__ __launch_bounds__(512, 4) void k1_lane(
    const float* __restrict__ queues, const float* __restrict__ waits,
    const float* __restrict__ elapsed, const int* __restrict__ lane_counts,
    const float* __restrict__ W1, const float* __restrict__ b1,
    const float* __restrict__ b2,
    const float* __restrict__ bq, const float* __restrict__ bk_, const float* __restrict__ bv_,
    const short* __restrict__ wpk,
    short* __restrict__ meanb)
{
    const int tid  = threadIdx.x;
    const int w    = tid >> 6, lane = tid & 63;
    const int nl   = lane & 15, kb = lane >> 4;
    const int base = blockIdx.x << 3;

    __shared__ __align__(512) short s_h1[8*2048];   // 32KB; stage C: wave-private qkv bufs
    __shared__ __align__(512) short s_emb[8*2048];  // 32KB

    const unsigned trofs = (unsigned)(kb*128 + nl*8);
    const short* Wpk2 = wpk;
    const short* WpkQ = wpk + 16384;
    const short* WpkK = wpk + 32768;
    const short* WpkV = wpk + 49152;

    // ---- stage A: wave w computes h1 for TLS w (col-major bf16 [col][16])
    {
        const int n = base + w;
        const float ev = elapsed[n];
        float qv = queues[n*16 + nl];
        float wv = waits [n*16 + nl];
        float qm[4], wmv[4];
        #pragma unroll
        for (int r = 0; r < 4; ++r){
            qm[r]  = __shfl(qv, 4*kb + r, 16);
            wmv[r] = __shfl(wv, 4*kb + r, 16);
        }
        #pragma unroll
        for (int i = 0; i < 8; ++i){
            int c = nl + 16*i;
            float w0 = W1[c], w1 = W1[128+c], w2 = W1[256+c], bb = b1[c];
            float v0 = fmaxf(fmaf(qm[0], w0, fmaf(wmv[0], w1, fmaf(ev, w2, bb))), 0.f);
            float v1 = fmaxf(fmaf(qm[1], w0, fmaf(wmv[1], w1, fmaf(ev, w2, bb))), 0.f);
            float v2 = fmaxf(fmaf(qm[2], w0, fmaf(wmv[2], w1, fmaf(ev, w2, bb))), 0.f);
            float v3 = fmaxf(fmaf(qm[3], w0, fmaf(wmv[3], w1, fmaf(ev, w2, bb))), 0.f);
            *(uint2*)&s_h1[w*2048 + c*16 + 4*kb] = make_uint2(pk2(v0,v1), pk2(v2,v3));
        }
    }
    __syncthreads();

    // ---- stage B: emb = relu(h1 @ W2 + b2); wave w owns cols [16w,16w+16); 2 TLS/iter
    {
        bf16x8 B2[4];
        gload4_wait(Wpk2 + ((w*4)*64 + lane)*8, B2[0], B2[1], B2[2], B2[3]);
        const int c0 = 16*w + nl;
        const float bb0 = b2[c0];
        for (int tp = 0; tp < 4; ++tp){
            unsigned abA = lds_lo(s_h1) + (2*tp)*4096 + trofs;
            bf16x4 trA[8], trB[8];
            #pragma unroll
            for (int kt = 0; kt < 4; ++kt){
                trA[2*kt]   = ds_tr(abA + kt*1024);
                trA[2*kt+1] = ds_tr(abA + kt*1024 + 512);
            }
            #pragma unroll
            for (int kt = 0; kt < 4; ++kt){
                trB[2*kt]   = ds_tr(abA + 4096 + kt*1024);
                trB[2*kt+1] = ds_tr(abA + 4096 + kt*1024 + 512);
            }
            lgkm0();
            f32x4 aA = {0.f,0.f,0.f,0.f}, aB = {0.f,0.f,0.f,0.f};
            #pragma unroll
            for (int kt = 0; kt < 4; ++kt){
                aA = MFMA16(cat44(trA[2*kt], trA[2*kt+1]), B2[kt], aA);
                aB = MFMA16(cat44(trB[2*kt], trB[2*kt+1]), B2[kt], aB);
            }
            *(uint2*)&s_emb[(2*tp)*2048 + c0*16 + 4*kb] =
                make_uint2(pk2(fmaxf(aA[0]+bb0,0.f), fmaxf(aA[1]+bb0,0.f)),
                           pk2(fmaxf(aA[2]+bb0,0.f), fmaxf(aA[3]+bb0,0.f)));
            *(uint2*)&s_emb[(2*tp+1)*2048 + c0*16 + 4*kb] =
                make_uint2(pk2(fmaxf(aB[0]+bb0,0.f), fmaxf(aB[1]+bb0,0.f)),
                           pk2(fmaxf(aB[2]+bb0,0.f), fmaxf(aB[3]+bb0,0.f)));
        }
    }
    __syncthreads();   // all stage-B reads of s_h1 done -> safe to overlay qkv bufs

    // ---- stage C + attention: wave w owns head w; 2 TLS/iter, both chains interleaved
    {
        bf16x8 BQ[4], BK[4], BV[4];
        gload4_wait(WpkQ + ((w*4)*64 + lane)*8, BQ[0], BQ[1], BQ[2], BQ[3]);
        gload4_wait(WpkK + ((w*4)*64 + lane)*8, BK[0], BK[1], BK[2], BK[3]);
        gload4_wait(WpkV + ((w*4)*64 + lane)*8, BV[0], BV[1], BV[2], BV[3]);
        const int c0 = 16*w + nl;
        const float xq = bq[c0], xk = bk_[c0], xv = bv_[c0];
        short* wbuf = s_h1 + w*2048;          // wave-private 4KB = 2 bufs x 2KB
        short* bufA = wbuf;                   // q[0,256) k[256,512) v[512,768) shorts
        short* bufB = wbuf + 1024;
        const f32x4 zero = {0.f,0.f,0.f,0.f};

        for (int tp = 0; tp < 4; ++tp){
            const int nA = base + 2*tp, nB = nA + 1;
            const int LA = lane_counts[nA], LB = lane_counts[nB];

            unsigned abA = lds_lo(s_emb) + (2*tp)*4096 + trofs;
            bf16x4 trA[8], trB[8];
            #pragma unroll
            for (int kt = 0; kt < 4; ++kt){
                trA[2*kt]   = ds_tr(abA + kt*1024);
                trA[2*kt+1] = ds_tr(abA + kt*1024 + 512);
            }
            #pragma unroll
            for (int kt = 0; kt < 4; ++kt){
                trB[2*kt]   = ds_tr(abA + 4096 + kt*1024);
                trB[2*kt+1] = ds_tr(abA + 4096 + kt*1024 + 512);
            }
            lgkm0();
            f32x4 qA=zero, kA2=zero, vA=zero, qB=zero, kB2=zero, vB=zero;
            #pragma unroll
            for (int kt = 0; kt < 4; ++kt){
                bf16x8 EA = cat44(trA[2*kt], trA[2*kt+1]);
                bf16x8 EB = cat44(trB[2*kt], trB[2*kt+1]);
                qA  = MFMA16(EA, BQ[kt], qA);   qB  = MFMA16(EB, BQ[kt], qB);
                kA2 = MFMA16(EA, BK[kt], kA2);  kB2 = MFMA16(EB, BK[kt], kB2);
                vA  = MFMA16(EA, BV[kt], vA);   vB  = MFMA16(EB, BV[kt], vB);
            }
            *(uint2*)&bufA[nl*16 + 4*kb] =
                make_uint2(pk2(qA[0]+xq, qA[1]+xq), pk2(qA[2]+xq, qA[3]+xq));
            *(uint2*)&bufA[256 + nl*16 + 4*kb] =
                make_uint2(pk2(kA2[0]+xk, kA2[1]+xk), pk2(kA2[2]+xk, kA2[3]+xk));
            *(uint2*)&bufA[512 + nl*16 + 4*kb] =
                make_uint2(pk2(vA[0]+xv, vA[1]+xv), pk2(vA[2]+xv, vA[3]+xv));
            *(uint2*)&bufB[nl*16 + 4*kb] =
                make_uint2(pk2(qB[0]+xq, qB[1]+xq), pk2(qB[2]+xq, qB[3]+xq));
            *(uint2*)&bufB[256 + nl*16 + 4*kb] =
                make_uint2(pk2(kB2[0]+xk, kB2[1]+xk), pk2(kB2[2]+xk, kB2[3]+xk));
            *(uint2*)&bufB[512 + nl*16 + 4*kb] =
                make_uint2(pk2(vB[0]+xv, vB[1]+xv), pk2(vB[2]+xv, vB[3]+xv));
            lgkm0();

            const unsigned baA = lds_lo(bufA), baB = lds_lo(bufB);
            bf16x4 qfA = ds_tr(baA + trofs);
            bf16x4 kfA = ds_tr(baA + 512 + trofs);
            bf16x4 qfB = ds_tr(baB + trofs);
            bf16x4 kfB = ds_tr(baB + 512 + trofs);
            bf16x4 vfA = *(const bf16x4*)&bufA[512 + nl*16 + 4*kb];
            bf16x4 vfB = *(const bf16x4*)&bufB[512 + nl*16 + 4*kb];
            lgkm0();

            f32x4 stA = MFMA16(cat40(kfA), cat40(qfA), zero);  // rows j=4kb+r, col i=nl
            f32x4 stB = MFMA16(cat40(kfB), cat40(qfB), zero);
            float prA[4], psA = 0.f, prB[4], psB = 0.f;
            #pragma unroll
            for (int r = 0; r < 4; ++r){
                prA[r] = (4*kb+r < LA) ? __expf(stA[r]*0.25f) : 0.f;
                prB[r] = (4*kb+r < LB) ? __expf(stB[r]*0.25f) : 0.f;
                psA += prA[r];  psB += prB[r];
            }
            psA += __shfl_xor(psA, 16);  psB += __shfl_xor(psB, 16);
            psA += __shfl_xor(psA, 32);  psB += __shfl_xor(psB, 32);
            const float invA = 1.f/psA, invB = 1.f/psB;
            union { bf16x8 v; unsigned u[4]; } PA, PB;
            PA.u[0] = pk2(prA[0]*invA, prA[1]*invA);
            PA.u[1] = pk2(prA[2]*invA, prA[3]*invA);
            PA.u[2] = 0; PA.u[3] = 0;
            PB.u[0] = pk2(prB[0]*invB, prB[1]*invB);
            PB.u[1] = pk2(prB[2]*invB, prB[3]*invB);
            PB.u[2] = 0; PB.u[3] = 0;
            f32x4 ctxA = MFMA16(PA.v, cat40(vfA), zero);       // rows i=4kb+r, col d=nl
            f32x4 ctxB = MFMA16(PB.v, cat40(vfB), zero);
            float pmA = 0.f, pmB = 0.f;
            #pragma unroll
            for (int r = 0; r < 4; ++r){
                if (4*kb+r < LA) pmA += ctxA[r];
                if (4*kb+r < LB) pmB += ctxB[r];
            }
            pmA += __shfl_xor(pmA, 16);  pmB += __shfl_xor(pmB, 16);
            pmA += __shfl_xor(pmA, 32);  pmB += __shfl_xor(pmB, 32);
            if (kb == 0){
                meanb[((nA>>4)<<11) + c0*16 + (nA&15)] = f2bf(pmA / (float)LA);
                meanb[((nB>>4)<<11) + c0*16 + (nB&15)] = f2bf(pmB / (float)LB);
            }
        }
    }
}

// ============ kernel 2: tail, 32 TLS/block, 8 waves (2 n-tiles per wave) ============
__global__ __launch_bounds__(512, 2) void k2_tail(
    const float* __restrict__ phase_onehot, const float* __restrict__ elapsed,
    const int* __restrict__ region_ids, const float* __restrict__ region_table,
    const float* __restrict__ Wp1, const float* __restrict__ bp1, const float* __restrict__ bp2,
    const float* __restrict__ bo,
    const float* __restrict__ bf1, const float* __restrict__ bf2_,
    const float* __restrict__ Wm, const float* __restrict__ bm,
    const float* __restrict__ Wval, const float* __restrict__ bval,
    const float* __restrict__ log_std,
    const short* __restrict__ wpk, const short* __restrict__ meanb,
    float* __restrict__ out)
{
    const int tid  = threadIdx.x;
    const int w    = tid >> 6, lane = tid & 63;
    const int nl   = lane & 15, kb = lane >> 4;
    const int base = blockIdx.x << 5;   // 32 TLS

    __shared__ __align__(512) short s_mean[2*2048];   // 8 KB
    __shared__ __align__(512) short s_ph1[2*2048];    // 8 KB
    __shared__ __align__(512) short s_fused[2*4608];  // 18 KB
    __shared__ __align__(512) short s_hf[2*4096];     // 16 KB
    __shared__ float s_part[8][2][16][2];             // 2 KB

    const unsigned trofs = (unsigned)(kb*128 + nl*8);
    const bf16x8* WpkO  = (const bf16x8*)(wpk + 65536);
    const bf16x8* WpkP2 = (const bf16x8*)(wpk + 81920);
    const bf16x8* WpkF1 = (const bf16x8*)(wpk + 98304);
    const bf16x8* WpkF2 = (const bf16x8*)(wpk + 172032);

    // 1. mean chunk -> LDS (512 x uint4 = 8 KB, one per thread)
    ((uint4*)s_mean)[tid] = ((const uint4*)(meanb + base*128))[tid];
    // 2. phase hidden: thread -> TLS r = tid>>4, 8 cols; 3. region: 2 cols
    {
        const int r = tid >> 4, cb = tid & 15, n = base + r;
        const float p0 = phase_onehot[n*4+0], p1 = phase_onehot[n*4+1];
        const float p2 = phase_onehot[n*4+2], p3 = phase_onehot[n*4+3];
        const float ev = elapsed[n];
        #pragma unroll
        for (int jc = 0; jc < 8; ++jc){
            int c = cb*8 + jc;
            float a = fmaf(p0, Wp1[c], fmaf(p1, Wp1[128+c], fmaf(p2, Wp1[256+c],
                      fmaf(p3, Wp1[384+c], fmaf(ev, Wp1[512+c], bp1[c])))));
            s_ph1[(r>>4)*2048 + c*16 + (r&15)] = f2bf(fmaxf(a, 0.f));
        }
        const int rid = region_ids[n];
        const int cc = cb*2;
        s_fused[(r>>4)*4608 + (256+cc)*16 + (r&15)]   = f2bf(region_table[rid*32 + cc]);
        s_fused[(r>>4)*4608 + (256+cc+1)*16 + (r&15)] = f2bf(region_table[rid*32 + cc + 1]);
    }
    __syncthreads();

    // 4. Wo (no relu, from mean) / Wp2 (relu, from ph1): waves 0-3 Wo, waves 4-7 Wp2
    {
        const int g  = w >> 2;        // 0: Wo, 1: Wp2
        const int q2 = w & 3;         // nt pair {2q2, 2q2+1}
        const bf16x8* WB  = g ? WpkP2 : WpkO;
        const short* Asrc = g ? s_ph1 : s_mean;
        bf16x8 B[8];
        #pragma unroll
        for (int j = 0; j < 2; ++j)
            #pragma unroll
            for (int kt = 0; kt < 4; ++kt)
                B[j*4+kt] = WB[((2*q2+j)*4+kt)*64 + lane];
        #pragma unroll
        for (int mt = 0; mt < 2; ++mt){
            unsigned ab = lds_lo(Asrc) + mt*4096 + trofs;
            bf16x4 t[8];
            #pragma unroll
            for (int kt = 0; kt < 4; ++kt){
                t[2*kt]   = ds_tr(ab + kt*1024);
                t[2*kt+1] = ds_tr(ab + kt*1024 + 512);
            }
            lgkm0();
            bf16x8 A[4];
            #pragma unroll
            for (int kt = 0; kt < 4; ++kt) A[kt] = cat44(t[2*kt], t[2*kt+1]);
            #pragma unroll
            for (int j = 0; j < 2; ++j){
                const int c = (2*q2+j)*16 + nl;
                const float bb = g ? bp2[c] : bo[c];
                f32x4 acc = {0.f,0.f,0.f,0.f};
                #pragma unroll
                for (int kt = 0; kt < 4; ++kt) acc = MFMA16(A[kt], B[j*4+kt], acc);
                short* fb = s_fused + mt*4608 + (g ? (128+c)*16 : c*16);
                if (g){
                    *(uint2*)&fb[4*kb] =
                        make_uint2(pk2(fmaxf(acc[0]+bb,0.f), fmaxf(acc[1]+bb,0.f)),
                                   pk2(fmaxf(acc[2]+bb,0.f), fmaxf(acc[3]+bb,0.f)));
                } else {
                    *(uint2*)&fb[4*kb] =
                        make_uint2(pk2(acc[0]+bb, acc[1]+bb), pk2(acc[2]+bb, acc[3]+bb));
                }
            }
        }
    }
    __syncthreads();

    // 5. F1: hf = relu(fused @ Wf1 + bf1), K=288; wave w owns nt {2w, 2w+1}
    {
        bf16x8 A[2][9];
        #pragma unroll
        for (int mt = 0; mt < 2; ++mt){
            unsigned ab = lds_lo(s_fused) + mt*9216 + trofs;
            bf16x4 t[18];
            #pragma unroll
            for (int kt = 0; kt < 9; ++kt){
                t[2*kt]   = ds_tr(ab + kt*1024);
                t[2*kt+1] = ds_tr(ab + kt*1024 + 512);
            }
            lgkm0();
            #pragma unroll
            for (int kt = 0; kt < 9; ++kt) A[mt][kt] = cat44(t[2*kt], t[2*kt+1]);
        }
        #pragma unroll
        for (int j = 0; j < 2; ++j){
            const int nt = 2*w + j;
            bf16x8 Bf[9];
            #pragma unroll
            for (int kt = 0; kt < 9; ++kt) Bf[kt] = WpkF1[(nt*9+kt)*64 + lane];
            f32x4 a0 = {0.f,0.f,0.f,0.f}, a1 = a0;
            #pragma unroll
            for (int kt = 0; kt < 9; ++kt){
                a0 = MFMA16(A[0][kt], Bf[kt], a0);
                a1 = MFMA16(A[1][kt], Bf[kt], a1);
            }
            const int c = nt*16 + nl;
            const float bb = bf1[c];
            *(uint2*)&s_hf[c*16 + 4*kb] =
                make_uint2(pk2(fmaxf(a0[0]+bb,0.f), fmaxf(a0[1]+bb,0.f)),
                           pk2(fmaxf(a0[2]+bb,0.f), fmaxf(a0[3]+bb,0.f)));
            *(uint2*)&s_hf[4096 + c*16 + 4*kb] =
                make_uint2(pk2(fmaxf(a1[0]+bb,0.f), fmaxf(a1[1]+bb,0.f)),
                           pk2(fmaxf(a1[2]+bb,0.f), fmaxf(a1[3]+bb,0.f)));
        }
    }
    __syncthreads();

    // 6. F2 + heads epilogue: wave w owns nt {2w, 2w+1}
    {
        bf16x8 A[2][8];
        #pragma unroll
        for (int mt = 0; mt < 2; ++mt){
            unsigned ab = lds_lo(s_hf) + mt*8192 + trofs;
            bf16x4 t[16];
            #pragma unroll
            for (int kt = 0; kt < 8; ++kt){
                t[2*kt]   = ds_tr(ab + kt*1024);
                t[2*kt+1] = ds_tr(ab + kt*1024 + 512);
            }
            lgkm0();
            #pragma unroll
            for (int kt = 0; kt < 8; ++kt) A[mt][kt] = cat44(t[2*kt], t[2*kt+1]);
        }
        float sm0[4] = {0,0,0,0}, sv0[4] = {0,0,0,0};
        float sm1[4] = {0,0,0,0}, sv1[4] = {0,0,0,0};
        #pragma unroll
        for (int j = 0; j < 2; ++j){
            const int nt = 2*w + j;
            bf16x8 Bf[8];
            #pragma unroll
            for (int kt = 0; kt < 8; ++kt) Bf[kt] = WpkF2[(nt*8+kt)*64 + lane];
            f32x4 a0 = {0.f,0.f,0.f,0.f}, a1 = a0;
            #pragma unroll
            for (int kt = 0; kt < 8; ++kt){
                a0 = MFMA16(A[0][kt], Bf[kt], a0);
                a1 = MFMA16(A[1][kt], Bf[kt], a1);
            }
            const int c = nt*16 + nl;
            const float bb = bf2_[c], wm = Wm[c], wv = Wval[c];
            #pragma unroll
            for (int r = 0; r < 4; ++r){
                float h0 = fmaxf(a0[r]+bb, 0.f);
                float h1 = fmaxf(a1[r]+bb, 0.f);
                sm0[r] = fmaf(h0, wm, sm0[r]);  sv0[r] = fmaf(h0, wv, sv0[r]);
                sm1[r] = fmaf(h1, wm, sm1[r]);  sv1[r] = fmaf(h1, wv, sv1[r]);
            }
        }
        #pragma unroll
        for (int off = 1; off < 16; off <<= 1){
            #pragma unroll
            for (int r = 0; r < 4; ++r){
                sm0[r] += __shfl_xor(sm0[r], off);  sv0[r] += __shfl_xor(sv0[r], off);
                sm1[r] += __shfl_xor(sm1[r], off);  sv1[r] += __shfl_xor(sv1[r], off);
            }
        }
        if (nl == 0){
            #pragma unroll
            for (int r = 0; r < 4; ++r){
                s_part[w][0][4*kb+r][0] = sm0[r];  s_part[w][0][4*kb+r][1] = sv0[r];
                s_part[w][1][4*kb+r][0] = sm1[r];  s_part[w][1][4*kb+r][1] = sv1[r];
            }
        }
    }
    __syncthreads();

    // 7. finalize
    if (tid < 32){
        const int r = tid, n = base + r;
        float sm = bm[0], sv = bval[0];
        #pragma unroll
        for (int ww = 0; ww < 8; ++ww){
            sm += s_part[ww][r>>4][r&15][0];
            sv += s_part[ww][r>>4][r&15][1];
        }
        out[n]          = sm;
        out[NTLS + n]   = log_std[0];
        out[2*NTLS + n] = sv;
    }
}

extern "C" void kernel_launch(void* const* d_in, const int* in_sizes, int n_in,
                              void* d_out, int out_size, void* d_ws, size_t ws_size,
                              hipStream_t stream) {
    const float* queues       = (const float*)d_in[0];
    const float* waits        = (const float*)d_in[1];
    const float* phase_onehot = (const float*)d_in[2];
    const float* elapsed      = (const float*)d_in[3];
    const int*   lane_counts  = (const int*)d_in[4];
    const int*   region_ids   = (const int*)d_in[5];
    const float* W1  = (const float*)d_in[6];
    const float* b1  = (const float*)d_in[7];
    const float* W2  = (const float*)d_in[8];
    const float* b2  = (const float*)d_in[9];
    const float* Wq  = (const float*)d_in[10];
    const float* bq  = (const float*)d_in[11];
    const float* Wk  = (const float*)d_in[12];
    const float* bk  = (const float*)d_in[13];
    const float* Wv  = (const float*)d_in[14];
    const float* bv  = (const float*)d_in[15];
    const float* Wo  = (const float*)d_in[16];
    const float* bo  = (const float*)d_in[17];
    const float* Wp1 = (const float*)d_in[18];
    const float* bp1 = (const float*)d_in[19];
    const float* Wp2 = (const float*)d_in[20];
    const float* bp2 = (const float*)d_in[21];
    const float* region_table = (const float*)d_in[22];
    const float* Wf1 = (const float*)d_in[23];
    const float* bf1 = (const float*)d_in[24];
    const float* Wf2 = (const float*)d_in[25];
    const float* bf2 = (const float*)d_in[26];
    const float* Wm  = (const float*)d_in[27];
    const float* bm  = (const float*)d_in[28];
    const float* Wval = (const float*)d_in[29];
    const float* bval = (const float*)d_in[30];
    const float* log_std = (const float*)d_in[31];
    float* out = (float*)d_out;

    short* wpk   = (short*)d_ws;                          // 475136 B packed weights
    short* meanb = (short*)((char*)d_ws + 524288);        // 4 MB col-major-16 mean

    prepack<<<116, 256, 0, stream>>>(W2, Wq, Wk, Wv, Wo, Wp2, Wf1, Wf2, wpk);
    k1_lane<<<2048, 512, 0, stream>>>(
        queues, waits, elapsed, lane_counts,
        W1, b1, b2, bq, bk, bv, wpk, meanb);
    k2_tail<<<512, 512, 0, stream>>>(
        phase_onehot, elapsed, region_ids, region_table,
        Wp1, bp1, bp2, bo, bf1, bf2, Wm, bm, Wval, bval, log_std,
        wpk, meanb, out);
}